// Round 7
// baseline (69.664 us; speedup 1.0000x reference)
//
#include <hip/hip_runtime.h>

// Shapes fixed by the reference: B=1, S=4096, H=32, D=128, M=4096.
#define HH 32
#define DD 128
#define MM 4096
#define ROW_F4 1024          // H*D/4 float4 per token row
#define D_F4   32            // D/4 float4 per (h, m) row

typedef float v4f __attribute__((ext_vector_type(4)));

// ---------------- Pass A: per-(position,tensor) amax -> scales in d_ws ----
// Pure-read kernel: streams k/v token rows (contiguous 16KB per wave),
// writes only 2 floats per row (sc and r=1/sc). No second use of the data,
// so no rematerialization problem; HBM sees a near-pure sequential read.
__global__ __launch_bounds__(256)
void pass_scales(const float* __restrict__ kin,
                 const float* __restrict__ vin,
                 const float* __restrict__ unc,
                 const int*   __restrict__ cur_pos,
                 float* __restrict__ ws_sc,   // [2][MM]
                 float* __restrict__ ws_r,    // [2][MM]
                 int S)
{
    const int t    = threadIdx.x;
    const int lane = t & 63;
    const int w    = (blockIdx.x << 2) + (t >> 6);   // 0..2*MM-1
    const int m    = w >> 1;
    const int isV  = w & 1;

    int cp  = *cur_pos;
    int cpm = cp % MM; if (cpm < 0) cpm += MM;
    int s0  = m - cpm; if (s0 < 0) s0 += MM;
    const int s = (s0 < S) ? (s0 + MM * ((S - 1 - s0) >> 12)) : -1;  // MM=2^12
    if (s < 0) return;   // untouched position: pass B copies old data through

    const v4f* src = reinterpret_cast<const v4f*>(isV ? vin : kin)
                     + (size_t)s * ROW_F4;
    float am = 0.0f;
    #pragma unroll
    for (int c = 0; c < 16; ++c) {
        v4f a = src[c * 64 + lane];
        am = fmaxf(am, fmaxf(fmaxf(fabsf(a.x), fabsf(a.y)),
                             fmaxf(fabsf(a.z), fabsf(a.w))));
    }
    #pragma unroll
    for (int off = 32; off > 0; off >>= 1)
        am = fmaxf(am, __shfl_xor(am, off, 64));

    if (lane == 0) {
        const float u   = unc[s];
        const float div = (u > 0.1f) ? 224.0f : 448.0f;
        const float sc  = fmaxf(am / div, 1e-8f);
        ws_sc[isV * MM + m] = sc;
        ws_r [isV * MM + m] = 1.0f / sc;   // <=1ulp vs per-elem division
    }
}

// ---------------- Pass B: quantize + SEQUENTIAL writes --------------------
// Wave w owns a contiguous 16KB chunk of the output caches: tensor and h are
// fixed per wave, m spans 32 consecutive positions, and every iteration
// stores 1KB contiguous (fillBuffer-like write stream -> DRAM page locality).
// Input reads are 512B segments that hit L3 (pass A just streamed them).
__global__ __launch_bounds__(256)
void pass_quant(const float* __restrict__ kin,
                const float* __restrict__ vin,
                const float* __restrict__ kc_in,
                const float* __restrict__ vc_in,
                const float* __restrict__ ksc_in,
                const float* __restrict__ vsc_in,
                const int*   __restrict__ cur_pos,
                float* __restrict__ kc_out,
                float* __restrict__ vc_out,
                float* __restrict__ ksc_out,
                float* __restrict__ vsc_out,
                const float* __restrict__ ws_sc,
                const float* __restrict__ ws_r,
                int S)
{
    const int t    = threadIdx.x;
    const int lane = t & 63;
    const int w    = (blockIdx.x << 2) + (t >> 6);   // 0..8191
    const int isV  = w >> 12;                        // 4096 waves per tensor
    const int wt   = w & 4095;
    const int h    = wt >> 7;                        // 128 waves per h-plane
    const int mb   = (wt & 127) << 5;                // 32 m per wave
    const int d4   = lane & 31;
    const int half = lane >> 5;

    const v4f*  in_  = reinterpret_cast<const v4f*>(isV ? vin : kin);
    const v4f*  cin  = reinterpret_cast<const v4f*>(isV ? vc_in : kc_in);
    v4f*        cout = reinterpret_cast<v4f*>(isV ? vc_out : kc_out);
    const float* sin_ = isV ? vsc_in  : ksc_in;
    float*       sout = isV ? vsc_out : ksc_out;
    const float* wsc  = ws_sc + isV * MM;
    const float* wr   = ws_r  + isV * MM;

    int cp  = *cur_pos;
    int cpm = cp % MM; if (cpm < 0) cpm += MM;

    v4f* outbase = cout + (size_t)h * (MM * D_F4) + (size_t)mb * D_F4;

    #pragma unroll
    for (int i = 0; i < 16; ++i) {
        const int m  = mb + 2 * i + half;
        int s0 = m - cpm; if (s0 < 0) s0 += MM;
        const int s = (s0 < S) ? (s0 + MM * ((S - 1 - s0) >> 12)) : -1;

        const int rel = (2 * i + half) * D_F4 + d4;
        v4f q;
        if (s >= 0) {
            v4f val = in_[(size_t)s * ROW_F4 + h * D_F4 + d4];
            const float r = wr[m];
            q.x = fminf(fmaxf(val.x * r, -448.0f), 448.0f);
            q.y = fminf(fmaxf(val.y * r, -448.0f), 448.0f);
            q.z = fminf(fmaxf(val.z * r, -448.0f), 448.0f);
            q.w = fminf(fmaxf(val.w * r, -448.0f), 448.0f);
            if (d4 == 0) sout[h * MM + m] = wsc[m];
        } else {
            q = cin[(size_t)h * (MM * D_F4) + (size_t)m * D_F4 + d4];
            if (d4 == 0) sout[h * MM + m] = sin_[h * MM + m];
        }
        outbase[rel] = q;
    }
}

extern "C" void kernel_launch(void* const* d_in, const int* in_sizes, int n_in,
                              void* d_out, int out_size, void* d_ws, size_t ws_size,
                              hipStream_t stream) {
    const float* kin = (const float*)d_in[0];
    const float* vin = (const float*)d_in[1];
    const float* unc = (const float*)d_in[2];
    const float* kc  = (const float*)d_in[3];
    const float* vc  = (const float*)d_in[4];
    const float* ksc = (const float*)d_in[5];
    const float* vsc = (const float*)d_in[6];
    const int*   cp  = (const int*)d_in[7];
    const int S = in_sizes[2];   // B*S with B=1

    float* out  = (float*)d_out;
    float* kco  = out;
    float* vco  = kco + (size_t)HH * MM * DD;
    float* ksco = vco + (size_t)HH * MM * DD;
    float* vsco = ksco + (size_t)HH * MM;

    float* ws_sc = (float*)d_ws;            // 2*MM floats
    float* ws_r  = ws_sc + 2 * MM;          // 2*MM floats (64KB total)

    // Pass A: 2*MM rows, one wave each (4 waves / 256-thread block).
    pass_scales<<<(2 * MM) / 4, 256, 0, stream>>>(
        kin, vin, unc, cp, ws_sc, ws_r, S);

    // Pass B: 8192 waves x 16KB contiguous output chunks.
    pass_quant<<<(2 * MM * 2) / 4 / 2 * 2 / 2, 256, 0, stream>>>(   // = 2048
        kin, vin, kc, vc, ksc, vsc, cp, kco, vco, ksco, vsco, ws_sc, ws_r, S);
}

// Round 8
// 49.672 us; speedup vs baseline: 1.4025x; 1.4025x over previous
//
#include <hip/hip_runtime.h>

// Shapes fixed by the reference: B=1, S=4096, H=32, D=128, M=4096.
#define HH 32
#define DD 128
#define MM 4096
#define ROW_F4 1024          // H*D/4 float4 per token row
#define D_F4   32            // D/4 float4 per (h, m) row
#define TPB    4             // tokens per block (64KB LDS)

typedef float v4f __attribute__((ext_vector_type(4)));

__device__ __forceinline__ void gl_lds16(const v4f* g, v4f* l) {
    __builtin_amdgcn_global_load_lds(
        (const __attribute__((address_space(1))) unsigned int*)g,
        (__attribute__((address_space(3))) unsigned int*)l,
        16, 0, 0);
}

__device__ __forceinline__ int src_token(int m, int cpm, int S) {
    int s0 = m - cpm; if (s0 < 0) s0 += MM;
    return (s0 < S) ? (s0 + MM * ((S - 1 - s0) / MM)) : -1;
}

// Fused: block stages 4 consecutive token rows (64KB, contiguous HBM read)
// into LDS via global_load_lds, computes per-token amax (wave-local), then
// quantizes h-major so every block iteration writes 2KB-contiguous runs per
// h-plane (R6 showed sequential writes run at the 6.3TB/s copy ceiling while
// the old scattered 512B write granules ran at ~4.2TB/s).
__global__ __launch_bounds__(256)
void teleport_fused(const float* __restrict__ kin,
                    const float* __restrict__ vin,
                    const float* __restrict__ unc,
                    const float* __restrict__ kc_in,
                    const float* __restrict__ vc_in,
                    const float* __restrict__ ksc_in,
                    const float* __restrict__ vsc_in,
                    const int*   __restrict__ cur_pos,
                    float* __restrict__ kc_out,
                    float* __restrict__ vc_out,
                    float* __restrict__ ksc_out,
                    float* __restrict__ vsc_out,
                    int S)
{
    __shared__ v4f   sh[TPB * ROW_F4];   // 64 KB: [token][h][d4]
    __shared__ float sc_l[TPB];

    const int t    = threadIdx.x;
    const int lane = t & 63;
    const int wv   = t >> 6;             // wave = token slot 0..3
    const int b    = blockIdx.x;
    const int isV  = b >> 10;            // blocks 0..1023 = K, 1024..2047 = V
    const int mb   = (b & 1023) * TPB;

    const float* in_  = isV ? vin : kin;
    const float* cin  = isV ? vc_in : kc_in;
    float*       cout = isV ? vc_out : kc_out;
    const float* sin_ = isV ? vsc_in  : ksc_in;
    float*       sout = isV ? vsc_out : ksc_out;

    int cp  = *cur_pos;
    int cpm = cp % MM; if (cpm < 0) cpm += MM;

    // ---- stage this wave's token row into LDS (async direct-to-LDS) ----
    const int m = mb + wv;
    const int s = src_token(m, cpm, S);
    if (s >= 0) {
        const v4f* src = reinterpret_cast<const v4f*>(in_) + (size_t)s * ROW_F4;
        #pragma unroll
        for (int c = 0; c < 16; ++c)
            gl_lds16(src + c * 64 + lane, sh + wv * ROW_F4 + c * 64);
    } else {
        const v4f* cb = reinterpret_cast<const v4f*>(cin);
        #pragma unroll
        for (int c = 0; c < 16; ++c) {
            int f4 = c * 64 + lane;
            gl_lds16(cb + (size_t)(f4 >> 5) * (MM * D_F4) + (size_t)m * D_F4 + (f4 & 31),
                     sh + wv * ROW_F4 + c * 64);
        }
    }
    asm volatile("s_waitcnt vmcnt(0)" ::: "memory");

    // ---- per-token amax (wave reads only its own token: no barrier yet) --
    if (s >= 0) {
        float am = 0.0f;
        #pragma unroll
        for (int c = 0; c < 16; ++c) {
            v4f a = sh[wv * ROW_F4 + c * 64 + lane];
            am = fmaxf(am, fmaxf(fmaxf(fabsf(a.x), fabsf(a.y)),
                                 fmaxf(fabsf(a.z), fabsf(a.w))));
        }
        #pragma unroll
        for (int off = 32; off > 0; off >>= 1)
            am = fmaxf(am, __shfl_xor(am, off, 64));
        if (lane == 0) {
            const float u   = unc[s];
            const float div = (u > 0.1f) ? 224.0f : 448.0f;
            sc_l[wv] = fmaxf(am / div, 1e-8f);
        }
    }
    __syncthreads();

    // ---- quantize/copy from LDS; h-major sequential writes ----
    const int ml   = (t >> 5) & (TPB - 1);  // token slot 0..3
    const int d4   = t & 31;
    const int hoff = t >> 7;                // 0..1
    const int mq   = mb + ml;
    const int sq   = src_token(mq, cpm, S);
    const float r  = (sq >= 0) ? (1.0f / sc_l[ml]) : 1.0f;  // <=1ulp vs div

    v4f* coutv = reinterpret_cast<v4f*>(cout);
    #pragma unroll
    for (int i = 0; i < 16; ++i) {
        const int h = 2 * i + hoff;
        v4f a = sh[ml * ROW_F4 + h * D_F4 + d4];
        v4f q;
        if (sq >= 0) {
            q.x = fminf(fmaxf(a.x * r, -448.0f), 448.0f);
            q.y = fminf(fmaxf(a.y * r, -448.0f), 448.0f);
            q.z = fminf(fmaxf(a.z * r, -448.0f), 448.0f);
            q.w = fminf(fmaxf(a.w * r, -448.0f), 448.0f);
        } else {
            q = a;   // untouched position: copy old cache through unmodified
        }
        coutv[(size_t)h * (MM * D_F4) + (size_t)mq * D_F4 + d4] = q;
    }

    // ---- scales: [32 h] x [4 m] per block ----
    if (t < 128) {
        const int h   = t >> 2;
        const int mll = t & 3;
        const int msc = mb + mll;
        const int ss  = src_token(msc, cpm, S);
        sout[h * MM + msc] = (ss >= 0) ? sc_l[mll] : sin_[h * MM + msc];
    }
}

extern "C" void kernel_launch(void* const* d_in, const int* in_sizes, int n_in,
                              void* d_out, int out_size, void* d_ws, size_t ws_size,
                              hipStream_t stream) {
    const float* kin = (const float*)d_in[0];
    const float* vin = (const float*)d_in[1];
    const float* unc = (const float*)d_in[2];
    const float* kc  = (const float*)d_in[3];
    const float* vc  = (const float*)d_in[4];
    const float* ksc = (const float*)d_in[5];
    const float* vsc = (const float*)d_in[6];
    const int*   cp  = (const int*)d_in[7];
    const int S = in_sizes[2];   // B*S with B=1

    float* out  = (float*)d_out;
    float* kco  = out;
    float* vco  = kco + (size_t)HH * MM * DD;
    float* ksco = vco + (size_t)HH * MM * DD;
    float* vsco = ksco + (size_t)HH * MM;

    // 2 tensors x (MM/TPB) blocks.
    teleport_fused<<<2 * (MM / TPB), 256, 0, stream>>>(
        kin, vin, unc, kc, vc, ksc, vsc, cp, kco, vco, ksco, vsco, S);
}